// Round 1
// baseline (1559.138 us; speedup 1.0000x reference)
//
#include <hip/hip_runtime.h>

// GCNConvSC: out = x + (D^-1/2 (A+I) D^-1/2) x W + b
// Reordered vs reference (aggregate-then-GEMM, valid by linearity; fp32
// reorder error ~1e-5 << 0.114 threshold). Scratch: only deg/dis (N floats).
//
// Pipeline (all on `stream`):
//  1. k_deg_init    deg[i] = 1 (self loop)
//  2. k_deg_count   deg[dst] += 1 per edge (fp32 atomics, exact for counts)
//  3. k_dis         deg -> rsqrt(deg) in place
//  4. k_agg_init    out[i,:] = x[i,:] * dis[i]^2          (self-loop term)
//  5. k_scatter     out[dst,:] += x[src,:] * dis[s]*dis[d] (wave per edge)
//  6. k_gemm_res    out[i,:] = x[i,:] + out_agg[i,:] @ W + b  (in-place tile)

__global__ void k_deg_init(float* __restrict__ deg, int N) {
    int i = blockIdx.x * blockDim.x + threadIdx.x;
    if (i < N) deg[i] = 1.0f;
}

__global__ void k_deg_count(const int* __restrict__ dst, float* __restrict__ deg, int E) {
    int e = blockIdx.x * blockDim.x + threadIdx.x;
    if (e < E) atomicAdd(&deg[dst[e]], 1.0f);
}

__global__ void k_dis(float* __restrict__ deg, int N) {
    int i = blockIdx.x * blockDim.x + threadIdx.x;
    if (i < N) deg[i] = rsqrtf(deg[i]);  // deg >= 1 always (self loop)
}

__global__ void k_agg_init(const float* __restrict__ x, const float* __restrict__ dis,
                           float* __restrict__ out, int N) {
    int t = blockIdx.x * blockDim.x + threadIdx.x;
    int total = N * 32;  // 32 float4 per row
    if (t < total) {
        int i = t >> 5, q = t & 31;
        float s = dis[i];
        s *= s;
        float4 v = ((const float4*)x)[(size_t)i * 32 + q];
        v.x *= s; v.y *= s; v.z *= s; v.w *= s;
        ((float4*)out)[(size_t)i * 32 + q] = v;
    }
}

// one wave (64 lanes) per edge; lane handles 2 consecutive cols (float2)
__global__ void k_scatter(const float* __restrict__ x, const int* __restrict__ ei,
                          const float* __restrict__ dis, float* __restrict__ out, int E) {
    int lane = threadIdx.x & 63;
    int wid  = (blockIdx.x * blockDim.x + threadIdx.x) >> 6;
    int nw   = (gridDim.x * blockDim.x) >> 6;
    for (int e = wid; e < E; e += nw) {
        int s = ei[e];
        int d = ei[E + e];
        float nrm = dis[s] * dis[d];
        float2 v = ((const float2*)(x + (size_t)s * 128))[lane];
        float* o = out + (size_t)d * 128 + lane * 2;
        atomicAdd(o,     v.x * nrm);
        atomicAdd(o + 1, v.y * nrm);
    }
}

// In-place: out_row = x_row + agg_row @ W + b.  128 rows/block, 1024 threads,
// thread tile 4 rows x 4 cols. W (64KB) + x-tile 128x132 (66KB) in LDS.
__global__ __launch_bounds__(1024) void k_gemm_res(
    const float* __restrict__ x, const float* __restrict__ W,
    const float* __restrict__ b, float* out, int N) {
    __shared__ float Wl[128 * 128];
    __shared__ float xt[128 * 132];  // +4 pad per row (keeps 16B alignment)

    int tid = threadIdx.x;
    // stage W (row-major [k][j]) as float4s
    for (int i = tid; i < 128 * 32; i += 1024)
        ((float4*)Wl)[i] = ((const float4*)W)[i];

    int r0 = blockIdx.x * 128;
    // stage agg tile (from out) into LDS
    for (int i = tid; i < 128 * 32; i += 1024) {
        int r = i >> 5, kq = i & 31;
        float4 v = make_float4(0.f, 0.f, 0.f, 0.f);
        if (r0 + r < N) v = *(const float4*)(out + (size_t)(r0 + r) * 128 + kq * 4);
        *(float4*)(xt + r * 132 + kq * 4) = v;
    }
    __syncthreads();

    int tx = tid & 31, ty = tid >> 5;  // 32 col-groups x 32 row-groups
    int j0 = tx * 4;
    const float* xrow0 = xt + (ty * 4) * 132;

    float acc[4][4] = {};
    for (int k = 0; k < 128; k += 4) {
        float xsv[4][4];
#pragma unroll
        for (int rr = 0; rr < 4; ++rr) {
            float4 t = *(const float4*)(xrow0 + rr * 132 + k);  // broadcast read
            xsv[rr][0] = t.x; xsv[rr][1] = t.y; xsv[rr][2] = t.z; xsv[rr][3] = t.w;
        }
#pragma unroll
        for (int kk = 0; kk < 4; ++kk) {
            float4 w = *(const float4*)(Wl + (k + kk) * 128 + j0);
#pragma unroll
            for (int rr = 0; rr < 4; ++rr) {
                acc[rr][0] = fmaf(xsv[rr][kk], w.x, acc[rr][0]);
                acc[rr][1] = fmaf(xsv[rr][kk], w.y, acc[rr][1]);
                acc[rr][2] = fmaf(xsv[rr][kk], w.z, acc[rr][2]);
                acc[rr][3] = fmaf(xsv[rr][kk], w.w, acc[rr][3]);
            }
        }
    }

    float4 bv = *(const float4*)(b + j0);
#pragma unroll
    for (int rr = 0; rr < 4; ++rr) {
        int r = r0 + ty * 4 + rr;
        if (r < N) {
            float4 xv = *(const float4*)(x + (size_t)r * 128 + j0);
            float4 o;
            o.x = xv.x + acc[rr][0] + bv.x;
            o.y = xv.y + acc[rr][1] + bv.y;
            o.z = xv.z + acc[rr][2] + bv.z;
            o.w = xv.w + acc[rr][3] + bv.w;
            *(float4*)(out + (size_t)r * 128 + j0) = o;
        }
    }
}

extern "C" void kernel_launch(void* const* d_in, const int* in_sizes, int n_in,
                              void* d_out, int out_size, void* d_ws, size_t ws_size,
                              hipStream_t stream) {
    const float* x  = (const float*)d_in[0];
    const int*   ei = (const int*)d_in[1];   // [2, E] row-major: src then dst
    const float* W  = (const float*)d_in[2];
    const float* b  = (const float*)d_in[3];
    float* out = (float*)d_out;

    int N = in_sizes[0] / 128;
    int E = in_sizes[1] / 2;

    float* deg = (float*)d_ws;  // N floats; becomes dis after k_dis

    k_deg_init<<<(N + 255) / 256, 256, 0, stream>>>(deg, N);
    k_deg_count<<<(E + 255) / 256, 256, 0, stream>>>(ei + E, deg, E);
    k_dis<<<(N + 255) / 256, 256, 0, stream>>>(deg, N);
    k_agg_init<<<(N * 32 + 255) / 256, 256, 0, stream>>>(x, deg, out, N);
    k_scatter<<<4096, 256, 0, stream>>>(x, ei, deg, out, E);
    k_gemm_res<<<(N + 127) / 128, 1024, 0, stream>>>(x, W, b, out, N);
}

// Round 2
// 756.135 us; speedup vs baseline: 2.0620x; 2.0620x over previous
//
#include <hip/hip_runtime.h>

// GCNConvSC: out = x + (D^-1/2 (A+I) D^-1/2) x W + b
// R2: scatter-atomics (R1: 1301us, atomic-unit-bound, 3% VALU, 20% HBM)
// replaced by device-built CSR + gather-aggregate. Aggregate-then-GEMM
// reorder kept (valid by linearity).
//
// Pipeline:
//  0. memsetAsync  cnt = 0
//  1. k_cnt        cnt[dst]++ per edge (int atomics)
//  2. k_scan       single-block scan: ptr=exscan(cnt), fill=ptr, dis=rsqrt(cnt+1), ptr[N]=E
//  3. k_fill       csr_src[atomicAdd(&fill[dst],1)] = src
//  4. k_gather     wave/node: out[d,:] = dis[d]*(sum_s dis[s]*x[s,:] + dis[d]*x[d,:])
//  5. k_gemm_res   out[i,:] = x[i,:] + out[i,:] @ W + b  (in-place 128-row tiles)

__global__ void k_cnt(const int* __restrict__ dst, int* __restrict__ cnt, int E) {
    int e = blockIdx.x * blockDim.x + threadIdx.x;
    if (e < E) atomicAdd(&cnt[dst[e]], 1);
}

__global__ __launch_bounds__(1024) void k_scan(const int* __restrict__ cnt,
                                               float* __restrict__ dis,
                                               int* __restrict__ ptr,
                                               int* __restrict__ fill, int N) {
    __shared__ int part[1024];
    int tid = threadIdx.x;
    int chunk = (N + 1023) / 1024;
    int lo = tid * chunk;
    int hi = min(lo + chunk, N);
    int s = 0;
    for (int i = lo; i < hi; ++i) s += cnt[i];
    part[tid] = s;
    __syncthreads();
    // Hillis-Steele inclusive scan over 1024 partials
    for (int off = 1; off < 1024; off <<= 1) {
        int v = (tid >= off) ? part[tid - off] : 0;
        __syncthreads();
        part[tid] += v;
        __syncthreads();
    }
    int run = (tid == 0) ? 0 : part[tid - 1];
    for (int i = lo; i < hi; ++i) {
        int c = cnt[i];
        ptr[i] = run;
        fill[i] = run;
        dis[i] = rsqrtf((float)(c + 1));  // +1 self loop
        run += c;
    }
    if (tid == 1023) ptr[N] = part[1023];
}

__global__ void k_fill(const int* __restrict__ ei, int* __restrict__ fill,
                       int* __restrict__ csr_src, int E) {
    int e = blockIdx.x * blockDim.x + threadIdx.x;
    if (e < E) {
        int s = ei[e];
        int d = ei[E + e];
        int pos = atomicAdd(&fill[d], 1);
        csr_src[pos] = s;
    }
}

// one wave per node; lane covers 2 consecutive cols (float2, 512B/row coalesced)
__global__ __launch_bounds__(256) void k_gather(const float* __restrict__ x,
                                                const int* __restrict__ csr_src,
                                                const int* __restrict__ ptr,
                                                const float* __restrict__ dis,
                                                float* __restrict__ out, int N) {
    int lane = threadIdx.x & 63;
    int node = (blockIdx.x * blockDim.x + threadIdx.x) >> 6;
    if (node >= N) return;
    int lo = ptr[node];
    int hi = ptr[node + 1];
    float dd = dis[node];

    float2 xv = ((const float2*)(x + (size_t)node * 128))[lane];
    float2 acc = make_float2(dd * xv.x, dd * xv.y);  // self-loop term (pre dd scale)

    int j = lo;
    for (; j + 1 < hi; j += 2) {  // 2 independent row loads in flight
        int s0 = __builtin_amdgcn_readfirstlane(csr_src[j]);
        int s1 = __builtin_amdgcn_readfirstlane(csr_src[j + 1]);
        float2 v0 = ((const float2*)(x + (size_t)s0 * 128))[lane];
        float2 v1 = ((const float2*)(x + (size_t)s1 * 128))[lane];
        float w0 = dis[s0];
        float w1 = dis[s1];
        acc.x = fmaf(w0, v0.x, acc.x);
        acc.y = fmaf(w0, v0.y, acc.y);
        acc.x = fmaf(w1, v1.x, acc.x);
        acc.y = fmaf(w1, v1.y, acc.y);
    }
    if (j < hi) {
        int s0 = __builtin_amdgcn_readfirstlane(csr_src[j]);
        float2 v0 = ((const float2*)(x + (size_t)s0 * 128))[lane];
        float w0 = dis[s0];
        acc.x = fmaf(w0, v0.x, acc.x);
        acc.y = fmaf(w0, v0.y, acc.y);
    }
    acc.x *= dd;
    acc.y *= dd;
    ((float2*)(out + (size_t)node * 128))[lane] = acc;
}

// In-place: out_row = x_row + agg_row @ W + b.  128 rows/block, 1024 threads,
// thread tile 4 rows x 4 cols. W (64KB) + agg-tile 128x132 (66KB) in LDS.
__global__ __launch_bounds__(1024) void k_gemm_res(
    const float* __restrict__ x, const float* __restrict__ W,
    const float* __restrict__ b, float* out, int N) {
    __shared__ float Wl[128 * 128];
    __shared__ float xt[128 * 132];  // +4 pad per row

    int tid = threadIdx.x;
    for (int i = tid; i < 128 * 32; i += 1024)
        ((float4*)Wl)[i] = ((const float4*)W)[i];

    int r0 = blockIdx.x * 128;
    for (int i = tid; i < 128 * 32; i += 1024) {
        int r = i >> 5, kq = i & 31;
        float4 v = make_float4(0.f, 0.f, 0.f, 0.f);
        if (r0 + r < N) v = *(const float4*)(out + (size_t)(r0 + r) * 128 + kq * 4);
        *(float4*)(xt + r * 132 + kq * 4) = v;
    }
    __syncthreads();

    int tx = tid & 31, ty = tid >> 5;
    int j0 = tx * 4;
    const float* xrow0 = xt + (ty * 4) * 132;

    float acc[4][4] = {};
    for (int k = 0; k < 128; k += 4) {
        float xsv[4][4];
#pragma unroll
        for (int rr = 0; rr < 4; ++rr) {
            float4 t = *(const float4*)(xrow0 + rr * 132 + k);
            xsv[rr][0] = t.x; xsv[rr][1] = t.y; xsv[rr][2] = t.z; xsv[rr][3] = t.w;
        }
#pragma unroll
        for (int kk = 0; kk < 4; ++kk) {
            float4 w = *(const float4*)(Wl + (k + kk) * 128 + j0);
#pragma unroll
            for (int rr = 0; rr < 4; ++rr) {
                acc[rr][0] = fmaf(xsv[rr][kk], w.x, acc[rr][0]);
                acc[rr][1] = fmaf(xsv[rr][kk], w.y, acc[rr][1]);
                acc[rr][2] = fmaf(xsv[rr][kk], w.z, acc[rr][2]);
                acc[rr][3] = fmaf(xsv[rr][kk], w.w, acc[rr][3]);
            }
        }
    }

    float4 bv = *(const float4*)(b + j0);
#pragma unroll
    for (int rr = 0; rr < 4; ++rr) {
        int r = r0 + ty * 4 + rr;
        if (r < N) {
            float4 xv = *(const float4*)(x + (size_t)r * 128 + j0);
            float4 o;
            o.x = xv.x + acc[rr][0] + bv.x;
            o.y = xv.y + acc[rr][1] + bv.y;
            o.z = xv.z + acc[rr][2] + bv.z;
            o.w = xv.w + acc[rr][3] + bv.w;
            *(float4*)(out + (size_t)r * 128 + j0) = o;
        }
    }
}

extern "C" void kernel_launch(void* const* d_in, const int* in_sizes, int n_in,
                              void* d_out, int out_size, void* d_ws, size_t ws_size,
                              hipStream_t stream) {
    const float* x  = (const float*)d_in[0];
    const int*   ei = (const int*)d_in[1];   // [2, E]: src row then dst row
    const float* W  = (const float*)d_in[2];
    const float* b  = (const float*)d_in[3];
    float* out = (float*)d_out;

    int N = in_sizes[0] / 128;
    int E = in_sizes[1] / 2;

    // workspace layout (bytes): cnt[N] | ptr[N+1] | fill[N] | dis[N] | csr_src[E]
    char* w = (char*)d_ws;
    int*   cnt     = (int*)w;                     w += (size_t)N * 4;
    int*   ptr     = (int*)w;                     w += (size_t)(N + 1) * 4;
    int*   fill    = (int*)w;                     w += (size_t)N * 4;
    float* dis     = (float*)w;                   w += (size_t)N * 4;
    int*   csr_src = (int*)w;                     // E ints

    hipMemsetAsync(cnt, 0, (size_t)N * 4, stream);
    k_cnt<<<(E + 255) / 256, 256, 0, stream>>>(ei + E, cnt, E);
    k_scan<<<1, 1024, 0, stream>>>(cnt, dis, ptr, fill, N);
    k_fill<<<(E + 255) / 256, 256, 0, stream>>>(ei, fill, csr_src, E);
    k_gather<<<((N * 64) + 255) / 256, 256, 0, stream>>>(x, csr_src, ptr, dis, out, N);
    k_gemm_res<<<(N + 127) / 128, 1024, 0, stream>>>(x, W, b, out, N);
}

// Round 3
// 475.441 us; speedup vs baseline: 3.2794x; 1.5904x over previous
//
#include <hip/hip_runtime.h>

// GCNConvSC: out = x + (D^-1/2 (A+I) D^-1/2) x W + b
// R3: (a) single-block k_scan (284us, 0.14% occupancy) -> 3-kernel parallel
//     scan (~15us); (b) gather: float2x64 -> float4x32 with half-waves
//     covering 2 edges concurrently (halves load/FMA issue count).
//
// Pipeline:
//  0. memsetAsync  cnt = 0
//  1. k_cnt        cnt[dst]++ per edge (int atomics)
//  2. k_part       per-block (1024-elem) sums of cnt
//  3. k_mid        1 block: exclusive-scan the 98 partials; ptr[N]=E
//  4. k_apply      block-local scan + offset -> ptr, fill, dis=rsqrt(cnt+1)
//  5. k_fill       csr_src[atomicAdd(&fill[dst],1)] = src
//  6. k_gather     wave/node: out[d,:] = dis[d]*(sum_s dis[s]*x[s,:] + dis[d]*x[d,:])
//  7. k_gemm_res   out[i,:] = x[i,:] + out[i,:] @ W + b  (in-place 128-row tiles)

#define SCAN_BLK 1024  // elements per scan block (256 thr x 4)

__global__ void k_cnt(const int* __restrict__ dst, int* __restrict__ cnt, int E) {
    int e = blockIdx.x * blockDim.x + threadIdx.x;
    if (e < E) atomicAdd(&cnt[dst[e]], 1);
}

__global__ __launch_bounds__(256) void k_part(const int* __restrict__ cnt,
                                              int* __restrict__ part, int N) {
    __shared__ int sums[256];
    int tid = threadIdx.x;
    int base = blockIdx.x * SCAN_BLK + tid * 4;
    int s = 0;
#pragma unroll
    for (int k = 0; k < 4; ++k) {
        int i = base + k;
        if (i < N) s += cnt[i];
    }
    sums[tid] = s;
    __syncthreads();
    for (int off = 128; off > 0; off >>= 1) {
        if (tid < off) sums[tid] += sums[tid + off];
        __syncthreads();
    }
    if (tid == 0) part[blockIdx.x] = sums[0];
}

__global__ __launch_bounds__(128) void k_mid(int* __restrict__ part,
                                             int* __restrict__ ptrN,
                                             int nblk, int E) {
    __shared__ int s[128];
    int tid = threadIdx.x;
    s[tid] = (tid < nblk) ? part[tid] : 0;
    __syncthreads();
    for (int off = 1; off < 128; off <<= 1) {
        int v = (tid >= off) ? s[tid - off] : 0;
        __syncthreads();
        s[tid] += v;
        __syncthreads();
    }
    if (tid < nblk) part[tid] = tid ? s[tid - 1] : 0;  // exclusive
    if (tid == 0) ptrN[0] = E;                         // ptr[N]
}

__global__ __launch_bounds__(256) void k_apply(const int* __restrict__ cnt,
                                               const int* __restrict__ part,
                                               float* __restrict__ dis,
                                               int* __restrict__ ptr,
                                               int* __restrict__ fill, int N) {
    __shared__ int sums[256];
    int tid = threadIdx.x;
    int base = blockIdx.x * SCAN_BLK + tid * 4;
    int c[4];
    int s = 0;
#pragma unroll
    for (int k = 0; k < 4; ++k) {
        int i = base + k;
        c[k] = (i < N) ? cnt[i] : 0;
        s += c[k];
    }
    sums[tid] = s;
    __syncthreads();
    for (int off = 1; off < 256; off <<= 1) {
        int v = (tid >= off) ? sums[tid - off] : 0;
        __syncthreads();
        sums[tid] += v;
        __syncthreads();
    }
    int run = part[blockIdx.x] + (tid ? sums[tid - 1] : 0);
#pragma unroll
    for (int k = 0; k < 4; ++k) {
        int i = base + k;
        if (i < N) {
            ptr[i] = run;
            fill[i] = run;
            dis[i] = rsqrtf((float)(c[k] + 1));  // +1 self loop
            run += c[k];
        }
    }
}

__global__ void k_fill(const int* __restrict__ ei, int* __restrict__ fill,
                       int* __restrict__ csr_src, int E) {
    int e = blockIdx.x * blockDim.x + threadIdx.x;
    if (e < E) {
        int s = ei[e];
        int d = ei[E + e];
        int pos = atomicAdd(&fill[d], 1);
        csr_src[pos] = s;
    }
}

// one wave per node; half-wave h (32 lanes) processes edges j=lo+h, lo+h+2, ...
// lane covers 4 consecutive cols (float4; 32 lanes x 16B = full 512B row).
__global__ __launch_bounds__(256) void k_gather(const float* __restrict__ x,
                                                const int* __restrict__ csr_src,
                                                const int* __restrict__ ptr,
                                                const float* __restrict__ dis,
                                                float* __restrict__ out, int N) {
    int lane = threadIdx.x & 63;
    int half = lane >> 5, sub = lane & 31;
    int node = (blockIdx.x * blockDim.x + threadIdx.x) >> 6;
    if (node >= N) return;
    int lo = ptr[node];
    int hi = ptr[node + 1];
    float dd = dis[node];

    float4 acc = make_float4(0.f, 0.f, 0.f, 0.f);
    for (int j = lo + half; j < hi; j += 2) {
        int s = csr_src[j];                       // uniform within half-wave
        float w = dis[s];
        float4 v = ((const float4*)(x + (size_t)s * 128))[sub];
        acc.x = fmaf(w, v.x, acc.x);
        acc.y = fmaf(w, v.y, acc.y);
        acc.z = fmaf(w, v.z, acc.z);
        acc.w = fmaf(w, v.w, acc.w);
    }
    if (half == 0) {  // self-loop term, counted once
        float4 v = ((const float4*)(x + (size_t)node * 128))[sub];
        acc.x = fmaf(dd, v.x, acc.x);
        acc.y = fmaf(dd, v.y, acc.y);
        acc.z = fmaf(dd, v.z, acc.z);
        acc.w = fmaf(dd, v.w, acc.w);
    }
    acc.x += __shfl_xor(acc.x, 32);
    acc.y += __shfl_xor(acc.y, 32);
    acc.z += __shfl_xor(acc.z, 32);
    acc.w += __shfl_xor(acc.w, 32);
    if (half == 0) {
        acc.x *= dd; acc.y *= dd; acc.z *= dd; acc.w *= dd;
        ((float4*)(out + (size_t)node * 128))[sub] = acc;
    }
}

// In-place: out_row = x_row + agg_row @ W + b.  128 rows/block, 1024 threads,
// thread tile 4 rows x 4 cols. W (64KB) + agg-tile 128x132 (66KB) in LDS.
__global__ __launch_bounds__(1024) void k_gemm_res(
    const float* __restrict__ x, const float* __restrict__ W,
    const float* __restrict__ b, float* out, int N) {
    __shared__ float Wl[128 * 128];
    __shared__ float xt[128 * 132];  // +4 pad per row

    int tid = threadIdx.x;
    for (int i = tid; i < 128 * 32; i += 1024)
        ((float4*)Wl)[i] = ((const float4*)W)[i];

    int r0 = blockIdx.x * 128;
    for (int i = tid; i < 128 * 32; i += 1024) {
        int r = i >> 5, kq = i & 31;
        float4 v = make_float4(0.f, 0.f, 0.f, 0.f);
        if (r0 + r < N) v = *(const float4*)(out + (size_t)(r0 + r) * 128 + kq * 4);
        *(float4*)(xt + r * 132 + kq * 4) = v;
    }
    __syncthreads();

    int tx = tid & 31, ty = tid >> 5;
    int j0 = tx * 4;
    const float* xrow0 = xt + (ty * 4) * 132;

    float acc[4][4] = {};
    for (int k = 0; k < 128; k += 4) {
        float xsv[4][4];
#pragma unroll
        for (int rr = 0; rr < 4; ++rr) {
            float4 t = *(const float4*)(xrow0 + rr * 132 + k);
            xsv[rr][0] = t.x; xsv[rr][1] = t.y; xsv[rr][2] = t.z; xsv[rr][3] = t.w;
        }
#pragma unroll
        for (int kk = 0; kk < 4; ++kk) {
            float4 w = *(const float4*)(Wl + (k + kk) * 128 + j0);
#pragma unroll
            for (int rr = 0; rr < 4; ++rr) {
                acc[rr][0] = fmaf(xsv[rr][kk], w.x, acc[rr][0]);
                acc[rr][1] = fmaf(xsv[rr][kk], w.y, acc[rr][1]);
                acc[rr][2] = fmaf(xsv[rr][kk], w.z, acc[rr][2]);
                acc[rr][3] = fmaf(xsv[rr][kk], w.w, acc[rr][3]);
            }
        }
    }

    float4 bv = *(const float4*)(b + j0);
#pragma unroll
    for (int rr = 0; rr < 4; ++rr) {
        int r = r0 + ty * 4 + rr;
        if (r < N) {
            float4 xv = *(const float4*)(x + (size_t)r * 128 + j0);
            float4 o;
            o.x = xv.x + acc[rr][0] + bv.x;
            o.y = xv.y + acc[rr][1] + bv.y;
            o.z = xv.z + acc[rr][2] + bv.z;
            o.w = xv.w + acc[rr][3] + bv.w;
            *(float4*)(out + (size_t)r * 128 + j0) = o;
        }
    }
}

extern "C" void kernel_launch(void* const* d_in, const int* in_sizes, int n_in,
                              void* d_out, int out_size, void* d_ws, size_t ws_size,
                              hipStream_t stream) {
    const float* x  = (const float*)d_in[0];
    const int*   ei = (const int*)d_in[1];   // [2, E]: src row then dst row
    const float* W  = (const float*)d_in[2];
    const float* b  = (const float*)d_in[3];
    float* out = (float*)d_out;

    int N = in_sizes[0] / 128;
    int E = in_sizes[1] / 2;
    int nblk = (N + SCAN_BLK - 1) / SCAN_BLK;  // 98 for N=100000 (must be <=128)

    // ws layout: cnt[N] | ptr[N+1] | fill[N] | dis[N] | part[128] | csr_src[E]
    char* w = (char*)d_ws;
    int*   cnt     = (int*)w;   w += (size_t)N * 4;
    int*   ptr     = (int*)w;   w += (size_t)(N + 1) * 4;
    int*   fill    = (int*)w;   w += (size_t)N * 4;
    float* dis     = (float*)w; w += (size_t)N * 4;
    int*   part    = (int*)w;   w += 128 * 4;
    int*   csr_src = (int*)w;   // E ints

    hipMemsetAsync(cnt, 0, (size_t)N * 4, stream);
    k_cnt<<<(E + 255) / 256, 256, 0, stream>>>(ei + E, cnt, E);
    k_part<<<nblk, 256, 0, stream>>>(cnt, part, N);
    k_mid<<<1, 128, 0, stream>>>(part, ptr + N, nblk, E);
    k_apply<<<nblk, 256, 0, stream>>>(cnt, part, dis, ptr, fill, N);
    k_fill<<<(E + 255) / 256, 256, 0, stream>>>(ei, fill, csr_src, E);
    k_gather<<<((N * 64) + 255) / 256, 256, 0, stream>>>(x, csr_src, ptr, dis, out, N);
    k_gemm_res<<<(N + 127) / 128, 1024, 0, stream>>>(x, W, b, out, N);
}

// Round 4
// 395.243 us; speedup vs baseline: 3.9448x; 1.2029x over previous
//
#include <hip/hip_runtime.h>

// GCNConvSC: out = x + (D^-1/2 (A+I) D^-1/2) x W + b
// R4: (a) gather in bf16 (halves 819MB logical row fetch; quarter-wave = 4
//     edges in flight); (b) GEMM -> bf16 MFMA 16x16x32 (was fp32 VALU).
//     bf16 x-copy (xh) and bf16 agg live interleaved inside d_out:
//       out row r (512B): [0,256) = agg_bf16 row r, [256,512) = xh_bf16 row r
//     gemm block reads agg only from its own rows before overwriting -> safe.
//     No extra workspace vs R3. Error budget: bf16 rounding ~0.02 << 0.114.
//
// Pipeline:
//  1. k_cvt      xh[r] = bf16(x[r]) into out rows' second halves
//  2. memset+k_cnt  cnt[dst]++ per edge
//  3. k_part/k_mid/k_apply  parallel exclusive scan -> ptr, fill, dis
//  4. k_fill     csr_src[atomicAdd(&fill[dst],1)] = src   (known 133us; next target)
//  5. k_gather   wave/node, quarter-wave/edge: agg[d] = dd*(sum dis_s*xh[s] + dd*xh[d])
//  6. k_gemm     out[r,:] = x[r,:] + agg[r,:] @ W + b   (MFMA bf16, W^T staged in LDS)

typedef __attribute__((ext_vector_type(8))) short short8;   // 8 bf16 (4 VGPR)
typedef __attribute__((ext_vector_type(4))) float floatx4;  // MFMA C/D

__device__ inline unsigned bf16rne(float f) {
    unsigned u = __builtin_bit_cast(unsigned, f);
    return (u + 0x7FFFu + ((u >> 16) & 1u)) >> 16;
}
__device__ inline unsigned pack2(float lo, float hi) {
    return bf16rne(lo) | (bf16rne(hi) << 16);
}
__device__ inline float bflo(unsigned u) { return __builtin_bit_cast(float, u << 16); }
__device__ inline float bfhi(unsigned u) { return __builtin_bit_cast(float, u & 0xFFFF0000u); }

#define SCAN_BLK 1024

__global__ void k_cvt(const float* __restrict__ x, char* __restrict__ outc, int N) {
    int t = blockIdx.x * blockDim.x + threadIdx.x;  // N*16 groups of 8 cols
    if (t >= N * 16) return;
    int r = t >> 4, g = t & 15;
    const float* p = x + (size_t)r * 128 + g * 8;
    float4 a = *(const float4*)p;
    float4 c = *(const float4*)(p + 4);
    uint4 v;
    v.x = pack2(a.x, a.y); v.y = pack2(a.z, a.w);
    v.z = pack2(c.x, c.y); v.w = pack2(c.z, c.w);
    *(uint4*)(outc + (size_t)r * 512 + 256 + g * 16) = v;
}

__global__ void k_cnt(const int* __restrict__ dst, int* __restrict__ cnt, int E) {
    int e = blockIdx.x * blockDim.x + threadIdx.x;
    if (e < E) atomicAdd(&cnt[dst[e]], 1);
}

__global__ __launch_bounds__(256) void k_part(const int* __restrict__ cnt,
                                              int* __restrict__ part, int N) {
    __shared__ int sums[256];
    int tid = threadIdx.x;
    int base = blockIdx.x * SCAN_BLK + tid * 4;
    int s = 0;
#pragma unroll
    for (int k = 0; k < 4; ++k) {
        int i = base + k;
        if (i < N) s += cnt[i];
    }
    sums[tid] = s;
    __syncthreads();
    for (int off = 128; off > 0; off >>= 1) {
        if (tid < off) sums[tid] += sums[tid + off];
        __syncthreads();
    }
    if (tid == 0) part[blockIdx.x] = sums[0];
}

__global__ __launch_bounds__(128) void k_mid(int* __restrict__ part,
                                             int* __restrict__ ptrN,
                                             int nblk, int E) {
    __shared__ int s[128];
    int tid = threadIdx.x;
    s[tid] = (tid < nblk) ? part[tid] : 0;
    __syncthreads();
    for (int off = 1; off < 128; off <<= 1) {
        int v = (tid >= off) ? s[tid - off] : 0;
        __syncthreads();
        s[tid] += v;
        __syncthreads();
    }
    if (tid < nblk) part[tid] = tid ? s[tid - 1] : 0;
    if (tid == 0) ptrN[0] = E;
}

__global__ __launch_bounds__(256) void k_apply(const int* __restrict__ cnt,
                                               const int* __restrict__ part,
                                               float* __restrict__ dis,
                                               int* __restrict__ ptr,
                                               int* __restrict__ fill, int N) {
    __shared__ int sums[256];
    int tid = threadIdx.x;
    int base = blockIdx.x * SCAN_BLK + tid * 4;
    int c[4];
    int s = 0;
#pragma unroll
    for (int k = 0; k < 4; ++k) {
        int i = base + k;
        c[k] = (i < N) ? cnt[i] : 0;
        s += c[k];
    }
    sums[tid] = s;
    __syncthreads();
    for (int off = 1; off < 256; off <<= 1) {
        int v = (tid >= off) ? sums[tid - off] : 0;
        __syncthreads();
        sums[tid] += v;
        __syncthreads();
    }
    int run = part[blockIdx.x] + (tid ? sums[tid - 1] : 0);
#pragma unroll
    for (int k = 0; k < 4; ++k) {
        int i = base + k;
        if (i < N) {
            ptr[i] = run;
            fill[i] = run;
            dis[i] = rsqrtf((float)(c[k] + 1));
            run += c[k];
        }
    }
}

__global__ void k_fill(const int* __restrict__ ei, int* __restrict__ fill,
                       int* __restrict__ csr_src, int E) {
    int e = blockIdx.x * blockDim.x + threadIdx.x;
    if (e < E) {
        int s = ei[e];
        int d = ei[E + e];
        int pos = atomicAdd(&fill[d], 1);
        csr_src[pos] = s;
    }
}

// one wave per node; quarter-wave q (16 lanes x 16B = 256B bf16 row) handles
// edges j = lo+q, lo+q+4, ...  4 rows in flight per wave.
__global__ __launch_bounds__(256) void k_gather(char* __restrict__ outc,
                                                const int* __restrict__ csr_src,
                                                const int* __restrict__ ptr,
                                                const float* __restrict__ dis,
                                                int N) {
    int lane = threadIdx.x & 63;
    int q = lane >> 4, sub = lane & 15;
    int node = (blockIdx.x * blockDim.x + threadIdx.x) >> 6;
    if (node >= N) return;
    int lo = ptr[node], hi = ptr[node + 1];
    float dd = dis[node];

    float acc[8] = {0.f, 0.f, 0.f, 0.f, 0.f, 0.f, 0.f, 0.f};
    for (int j = lo + q; j < hi; j += 4) {
        int s = csr_src[j];
        float w = dis[s];
        uint4 v = *(const uint4*)(outc + (size_t)s * 512 + 256 + sub * 16);
        acc[0] = fmaf(w, bflo(v.x), acc[0]);
        acc[1] = fmaf(w, bfhi(v.x), acc[1]);
        acc[2] = fmaf(w, bflo(v.y), acc[2]);
        acc[3] = fmaf(w, bfhi(v.y), acc[3]);
        acc[4] = fmaf(w, bflo(v.z), acc[4]);
        acc[5] = fmaf(w, bfhi(v.z), acc[5]);
        acc[6] = fmaf(w, bflo(v.w), acc[6]);
        acc[7] = fmaf(w, bfhi(v.w), acc[7]);
    }
    if (q == 0) {  // self-loop term, once
        uint4 v = *(const uint4*)(outc + (size_t)node * 512 + 256 + sub * 16);
        acc[0] = fmaf(dd, bflo(v.x), acc[0]);
        acc[1] = fmaf(dd, bfhi(v.x), acc[1]);
        acc[2] = fmaf(dd, bflo(v.y), acc[2]);
        acc[3] = fmaf(dd, bfhi(v.y), acc[3]);
        acc[4] = fmaf(dd, bflo(v.z), acc[4]);
        acc[5] = fmaf(dd, bfhi(v.z), acc[5]);
        acc[6] = fmaf(dd, bflo(v.w), acc[6]);
        acc[7] = fmaf(dd, bfhi(v.w), acc[7]);
    }
#pragma unroll
    for (int i = 0; i < 8; ++i) {
        acc[i] += __shfl_xor(acc[i], 16);
        acc[i] += __shfl_xor(acc[i], 32);
    }
    if (q == 0) {
        uint4 o;
        o.x = pack2(dd * acc[0], dd * acc[1]);
        o.y = pack2(dd * acc[2], dd * acc[3]);
        o.z = pack2(dd * acc[4], dd * acc[5]);
        o.w = pack2(dd * acc[6], dd * acc[7]);
        *(uint4*)(outc + (size_t)node * 512 + sub * 16) = o;
    }
}

// MFMA GEMM: block = 256 thr (4 waves), 128 rows/block (wave: 2 row-tiles of 16).
// A = agg_bf16 (in out rows' first halves), B = W^T bf16 staged in LDS.
// C/D layout (verified m89/m91): col=lane&15, row=(lane>>4)*4+reg.
// A-frag: A[m=lane&15][k=quad*8+j]; B-frag symmetric (col n=lane&15, k=quad*8+j).
__global__ __launch_bounds__(256) void k_gemm(const float* __restrict__ x,
                                              const float* __restrict__ W,
                                              const float* __restrict__ bias,
                                              float* __restrict__ out, int N) {
    __shared__ short Wt[128 * 136];  // Wt[n][k], row stride 136 shorts = 272B (2-way-free banks)
    int tid = threadIdx.x;
    for (int i = tid; i < 8192; i += 256) {  // pairs of k for one n
        int n = i & 127, k2 = i >> 7;        // k = 2*k2, 2*k2+1
        float w0 = W[(size_t)(2 * k2) * 128 + n];
        float w1 = W[(size_t)(2 * k2 + 1) * 128 + n];
        *(unsigned*)(Wt + (size_t)n * 136 + 2 * k2) = pack2(w0, w1);
    }
    __syncthreads();

    int lane = tid & 63, wv = tid >> 6;
    int quad = lane >> 4, l16 = lane & 15;
    size_t rowb = (size_t)blockIdx.x * 128 + wv * 32;
    const char* aggc = (const char*)out;

    floatx4 acc[2][8];
#pragma unroll
    for (int rt = 0; rt < 2; ++rt)
#pragma unroll
        for (int c = 0; c < 8; ++c) acc[rt][c] = (floatx4)0.0f;

    size_t r0 = rowb + l16;      if (r0 >= (size_t)N) r0 = N - 1;  // pad rows: clamped, store-guarded
    size_t r1 = rowb + 16 + l16; if (r1 >= (size_t)N) r1 = N - 1;

    for (int ks = 0; ks < 4; ++ks) {
        int koff = (quad * 8 + ks * 32) * 2;  // byte offset into 256B bf16 row
        short8 a0 = *(const short8*)(aggc + r0 * 512 + koff);
        short8 a1 = *(const short8*)(aggc + r1 * 512 + koff);
#pragma unroll
        for (int c = 0; c < 8; ++c) {
            short8 bf = *(const short8*)(Wt + (size_t)(c * 16 + l16) * 136 + quad * 8 + ks * 32);
            acc[0][c] = __builtin_amdgcn_mfma_f32_16x16x32_bf16(a0, bf, acc[0][c], 0, 0, 0);
            acc[1][c] = __builtin_amdgcn_mfma_f32_16x16x32_bf16(a1, bf, acc[1][c], 0, 0, 0);
        }
    }

    // epilogue: out = x + acc + b (only after all A-frags for this wave's rows read)
#pragma unroll
    for (int rt = 0; rt < 2; ++rt) {
#pragma unroll
        for (int c = 0; c < 8; ++c) {
            float bb = bias[c * 16 + l16];
#pragma unroll
            for (int r = 0; r < 4; ++r) {
                size_t row = rowb + rt * 16 + quad * 4 + r;
                if (row < (size_t)N) {
                    size_t idx = row * 128 + c * 16 + l16;
                    out[idx] = x[idx] + acc[rt][c][r] + bb;
                }
            }
        }
    }
}

extern "C" void kernel_launch(void* const* d_in, const int* in_sizes, int n_in,
                              void* d_out, int out_size, void* d_ws, size_t ws_size,
                              hipStream_t stream) {
    const float* x  = (const float*)d_in[0];
    const int*   ei = (const int*)d_in[1];   // [2, E]: src row then dst row
    const float* W  = (const float*)d_in[2];
    const float* b  = (const float*)d_in[3];
    float* out = (float*)d_out;

    int N = in_sizes[0] / 128;
    int E = in_sizes[1] / 2;
    int nblk = (N + SCAN_BLK - 1) / SCAN_BLK;  // 98 for N=100000 (<=128)

    // ws: cnt[N] | ptr[N+1] | fill[N] | dis[N] | part[128] | csr_src[E]
    char* w = (char*)d_ws;
    int*   cnt     = (int*)w;   w += (size_t)N * 4;
    int*   ptr     = (int*)w;   w += (size_t)(N + 1) * 4;
    int*   fill    = (int*)w;   w += (size_t)N * 4;
    float* dis     = (float*)w; w += (size_t)N * 4;
    int*   part    = (int*)w;   w += 128 * 4;
    int*   csr_src = (int*)w;

    k_cvt<<<(N * 16 + 255) / 256, 256, 0, stream>>>(x, (char*)out, N);
    hipMemsetAsync(cnt, 0, (size_t)N * 4, stream);
    k_cnt<<<(E + 255) / 256, 256, 0, stream>>>(ei + E, cnt, E);
    k_part<<<nblk, 256, 0, stream>>>(cnt, part, N);
    k_mid<<<1, 128, 0, stream>>>(part, ptr + N, nblk, E);
    k_apply<<<nblk, 256, 0, stream>>>(cnt, part, dis, ptr, fill, N);
    k_fill<<<(E + 255) / 256, 256, 0, stream>>>(ei, fill, csr_src, E);
    k_gather<<<((size_t)N * 64 + 255) / 256, 256, 0, stream>>>((char*)out, csr_src, ptr, dis, N);
    k_gemm<<<(N + 127) / 128, 256, 0, stream>>>(x, W, b, out, N);
}